// Round 1
// baseline (259.958 us; speedup 1.0000x reference)
//
#include <hip/hip_runtime.h>
#include <hip/hip_bf16.h>

typedef unsigned short u16;
typedef __bf16 bf16;
typedef __attribute__((ext_vector_type(8))) __bf16 bf16x8;
typedef __attribute__((ext_vector_type(4))) __bf16 bf16x4;
typedef __attribute__((ext_vector_type(4))) float f32x4;

#define MFMA16(A,B,C) __builtin_amdgcn_mfma_f32_16x16x32_bf16(A,B,C,0,0,0)

constexpr int NTOK = 49;
constexpr int CH   = 128;
// softmax scale folded into exp2: SCALE * log2(e)
constexpr float CEXP = 0.17677669529663687f * 1.4426950408889634f;

__device__ __forceinline__ bf16x8 lds_v8(const u16* base, int byteoff) {
    return *reinterpret_cast<const bf16x8*>(reinterpret_cast<const char*>(base) + byteoff);
}
__device__ __forceinline__ void lds_st16(u16* base, int byteoff, bf16 v) {
    *reinterpret_cast<bf16*>(reinterpret_cast<char*>(base) + byteoff) = v;
}

// Convert weights fp32 -> bf16, TRANSPOSED so MFMA B-fragments read contiguous K.
// ws layout: Wqkv_t[384][128] then Wproj_t[128][128]
__global__ void prep_weights_kernel(const float* __restrict__ wqkv,
                                    const float* __restrict__ wproj,
                                    bf16* __restrict__ ws) {
    int i = blockIdx.x * 256 + threadIdx.x;
    if (i < 384 * 128) {
        int n = i >> 7, k = i & 127;
        ws[i] = (bf16)wqkv[k * 384 + n];
    }
    if (i < 128 * 128) {
        int n = i >> 7, k = i & 127;
        ws[384 * 128 + i] = (bf16)wproj[k * 128 + n];
    }
}

__launch_bounds__(256, 1)
__global__ void fused_window_attn(const float* __restrict__ x,
                                  const bf16* __restrict__ wqkv_t,
                                  const bf16* __restrict__ wproj_t,
                                  const float* __restrict__ bias,
                                  float* __restrict__ out) {
    // Xs: x tile bf16 [64 rows][128 ch], 256B rows, swizzle byte^=((row&7)<<4). Reused as O tile.
    __shared__ __align__(16) u16 Xs[64 * 128];
    // Q,K: [head][64 rows][stride 40 elems] (80B rows, padding breaks pow2 conflicts)
    __shared__ __align__(16) u16 Qs[4][64 * 40];
    __shared__ __align__(16) u16 Ks[4][64 * 40];
    // V transposed: [head][dh 32][seq 64], 128B rows, swizzled
    __shared__ __align__(16) u16 Vt[4][32 * 64];
    // per-wave P scratch [64][64], 128B rows, swizzled
    __shared__ __align__(16) u16 Pb[4][64 * 64];

    const int tid  = threadIdx.x;
    const int blk  = blockIdx.x;
    const int wv   = tid >> 6;
    const int lane = tid & 63;
    const int lr   = lane & 15;   // A row / B col / D col within tile
    const int lg   = lane >> 4;   // k-group for A/B; row-group for D

    // ---------- phase 0: stage x -> Xs (bf16, swizzled); zero V seq-pad ----------
    const float* xw = x + (size_t)blk * (NTOK * CH);
    #pragma unroll
    for (int it = 0; it < 7; ++it) {
        int i = tid + it * 256;
        if (i < (NTOK * CH) / 4) {
            float4 v = reinterpret_cast<const float4*>(xw)[i];
            int e = i * 4, row = e >> 7, col = e & 127;
            bf16x4 pk = { (bf16)v.x, (bf16)v.y, (bf16)v.z, (bf16)v.w };
            *reinterpret_cast<bf16x4*>(reinterpret_cast<char*>(Xs)
                + row * 256 + ((col * 2) ^ ((row & 7) << 4))) = pk;
        }
    }
    {   // zero Vt seq columns 48..63 (bytes 96..127 of each row, swizzled) — 0*NaN guard
        int head = tid >> 6, r = (tid >> 1) & 31, hf = tid & 1;
        uint4 zz = {0, 0, 0, 0};
        *reinterpret_cast<uint4*>(reinterpret_cast<char*>(Vt[head])
            + r * 128 + ((96 + hf * 16) ^ ((r & 7) << 4))) = zz;
    }
    __syncthreads();

    // ---------- phase 1: QKV GEMM (49x128 @ 128x384) ----------
    bf16x8 af[4][4];  // A-frags [mtile][kstep] from Xs
    #pragma unroll
    for (int mt = 0; mt < 4; ++mt)
        #pragma unroll
        for (int ks = 0; ks < 4; ++ks) {
            int row = mt * 16 + lr;
            af[mt][ks] = lds_v8(Xs, row * 256 + ((ks * 64 + lg * 16) ^ ((row & 7) << 4)));
        }

    #pragma unroll
    for (int i = 0; i < 6; ++i) {          // wave owns 6 of the 24 n-tiles
        int ntg = wv * 6 + i;
        int c   = ntg * 16 + lr;           // output channel of this lane
        bf16x8 bw[4];
        const bf16* wrow = wqkv_t + c * 128 + lg * 8;
        #pragma unroll
        for (int ks = 0; ks < 4; ++ks)
            bw[ks] = *reinterpret_cast<const bf16x8*>(wrow + ks * 32);
        #pragma unroll
        for (int mt = 0; mt < 4; ++mt) {
            f32x4 a = {0.f, 0.f, 0.f, 0.f};
            #pragma unroll
            for (int ks = 0; ks < 4; ++ks) a = MFMA16(af[mt][ks], bw[ks], a);
            #pragma unroll
            for (int rg = 0; rg < 4; ++rg) {
                int r = mt * 16 + lg * 4 + rg;
                if (r < NTOK) {
                    bf16 vb = (bf16)a[rg];
                    if (c < 128) {
                        Qs[c >> 5][r * 40 + (c & 31)] = __builtin_bit_cast(u16, vb);
                    } else if (c < 256) {
                        int cc = c - 128;
                        Ks[cc >> 5][r * 40 + (cc & 31)] = __builtin_bit_cast(u16, vb);
                    } else {
                        int cc = c - 256, dh = cc & 31;
                        lds_st16(Vt[cc >> 5], dh * 128 + ((r * 2) ^ ((dh & 7) << 4)), vb);
                    }
                }
            }
        }
    }
    __syncthreads();

    // ---------- phase 2: per-head attention (wave wv == head h) ----------
    const int h = wv;
    bf16x8 qf[4], kf[4];
    #pragma unroll
    for (int t = 0; t < 4; ++t) {
        qf[t] = lds_v8(Qs[h], (t * 16 + lr) * 80 + lg * 16);
        kf[t] = lds_v8(Ks[h], (t * 16 + lr) * 80 + lg * 16);
    }
    f32x4 s[4][4];
    #pragma unroll
    for (int mt = 0; mt < 4; ++mt)
        #pragma unroll
        for (int nt = 0; nt < 4; ++nt) {
            f32x4 z = {0.f, 0.f, 0.f, 0.f};
            s[mt][nt] = MFMA16(qf[mt], kf[nt], z);  // S = q @ k^T (K=32, one step)
        }
    // mask seq columns >= 49 (nt==3, lr>=1)
    if (lr >= 1) {
        #pragma unroll
        for (int mt = 0; mt < 4; ++mt)
            #pragma unroll
            for (int rg = 0; rg < 4; ++rg) s[mt][3][rg] = -1e30f;
    }
    // wave-parallel softmax: rows live in 16-lane groups; reduce cols via shfl_xor
    float rs[4][4];
    #pragma unroll
    for (int mt = 0; mt < 4; ++mt) {
        #pragma unroll
        for (int rg = 0; rg < 4; ++rg) {
            float m = fmaxf(fmaxf(s[mt][0][rg], s[mt][1][rg]),
                            fmaxf(s[mt][2][rg], s[mt][3][rg]));
            #pragma unroll
            for (int d = 1; d < 16; d <<= 1) m = fmaxf(m, __shfl_xor(m, d));
            float l = 0.f;
            #pragma unroll
            for (int nt = 0; nt < 4; ++nt) {
                float e = exp2f((s[mt][nt][rg] - m) * CEXP);
                s[mt][nt][rg] = e;
                l += e;
            }
            #pragma unroll
            for (int d = 1; d < 16; d <<= 1) l += __shfl_xor(l, d);
            rs[mt][rg] = 1.f / l;   // fold normalization into O rescale
        }
    }
    // unnormalized P -> Pb (bf16, swizzled), D-layout -> A-layout via LDS
    #pragma unroll
    for (int mt = 0; mt < 4; ++mt)
        #pragma unroll
        for (int nt = 0; nt < 4; ++nt)
            #pragma unroll
            for (int rg = 0; rg < 4; ++rg) {
                int row = mt * 16 + lg * 4 + rg;
                int col = nt * 16 + lr;
                lds_st16(Pb[wv], row * 128 + ((col * 2) ^ ((row & 7) << 4)),
                         (bf16)s[mt][nt][rg]);
            }
    // O = P @ V  (K = 64 padded seq, 2 steps; V pad cols are zero)
    f32x4 o[4][2];
    #pragma unroll
    for (int mt = 0; mt < 4; ++mt) {
        f32x4 z = {0.f, 0.f, 0.f, 0.f};
        o[mt][0] = z; o[mt][1] = z;
    }
    #pragma unroll
    for (int ks = 0; ks < 2; ++ks) {
        bf16x8 vf2[2];
        #pragma unroll
        for (int ot = 0; ot < 2; ++ot) {
            int vr = ot * 16 + lr;  // dh row of Vt
            vf2[ot] = lds_v8(Vt[h], vr * 128 + ((ks * 64 + lg * 16) ^ ((vr & 7) << 4)));
        }
        #pragma unroll
        for (int mt = 0; mt < 4; ++mt) {
            int pr = mt * 16 + lr;
            bf16x8 pf = lds_v8(Pb[wv], pr * 128 + ((ks * 64 + lg * 16) ^ ((pr & 7) << 4)));
            #pragma unroll
            for (int ot = 0; ot < 2; ++ot) o[mt][ot] = MFMA16(pf, vf2[ot], o[mt][ot]);
        }
    }
    // rescale by 1/rowsum, write O tile into Xs (freed after phase 1)
    #pragma unroll
    for (int mt = 0; mt < 4; ++mt)
        #pragma unroll
        for (int ot = 0; ot < 2; ++ot)
            #pragma unroll
            for (int rg = 0; rg < 4; ++rg) {
                int r = mt * 16 + lg * 4 + rg;
                int c = h * 32 + ot * 16 + lr;
                lds_st16(Xs, r * 256 + ((c * 2) ^ ((r & 7) << 4)),
                         (bf16)(o[mt][ot][rg] * rs[mt][rg]));
            }
    __syncthreads();

    // ---------- phase 3: proj GEMM (49x128 @ 128x128) + bias ----------
    bf16x8 ofr[4][4];
    #pragma unroll
    for (int mt = 0; mt < 4; ++mt)
        #pragma unroll
        for (int ks = 0; ks < 4; ++ks) {
            int row = mt * 16 + lr;
            ofr[mt][ks] = lds_v8(Xs, row * 256 + ((ks * 64 + lg * 16) ^ ((row & 7) << 4)));
        }
    #pragma unroll
    for (int i = 0; i < 2; ++i) {          // wave owns 2 of the 8 n-tiles
        int ntg = wv * 2 + i;
        int c   = ntg * 16 + lr;
        bf16x8 bw[4];
        const bf16* wrow = wproj_t + c * 128 + lg * 8;
        #pragma unroll
        for (int ks = 0; ks < 4; ++ks)
            bw[ks] = *reinterpret_cast<const bf16x8*>(wrow + ks * 32);
        float bv = bias[c];
        #pragma unroll
        for (int mt = 0; mt < 4; ++mt) {
            f32x4 a = {0.f, 0.f, 0.f, 0.f};
            #pragma unroll
            for (int ks = 0; ks < 4; ++ks) a = MFMA16(ofr[mt][ks], bw[ks], a);
            #pragma unroll
            for (int rg = 0; rg < 4; ++rg) {
                int r = mt * 16 + lg * 4 + rg;
                if (r < NTOK)
                    out[((size_t)blk * NTOK + r) * CH + c] = a[rg] + bv;
            }
        }
    }
}

extern "C" void kernel_launch(void* const* d_in, const int* in_sizes, int n_in,
                              void* d_out, int out_size, void* d_ws, size_t ws_size,
                              hipStream_t stream) {
    const float* x     = (const float*)d_in[0];
    const float* wqkv  = (const float*)d_in[1];
    const float* wproj = (const float*)d_in[2];
    const float* bias  = (const float*)d_in[3];
    float* out = (float*)d_out;
    bf16* ws   = (bf16*)d_ws;

    constexpr size_t WS_NEED = (size_t)(384 * 128 + 128 * 128) * sizeof(u16);
    if (ws_size < WS_NEED) return;  // scratch too small: fail visibly (zero output)

    prep_weights_kernel<<<192, 256, 0, stream>>>(wqkv, wproj, ws);
    fused_window_attn<<<4096, 256, 0, stream>>>(x, ws, ws + 384 * 128, bias, out);
}

// Round 2
// 132.240 us; speedup vs baseline: 1.9658x; 1.9658x over previous
//
#include <hip/hip_runtime.h>
#include <hip/hip_bf16.h>

typedef unsigned short u16;
typedef __bf16 bf16;
typedef __attribute__((ext_vector_type(8))) __bf16 bf16x8;
typedef __attribute__((ext_vector_type(4))) __bf16 bf16x4;
typedef __attribute__((ext_vector_type(4))) float f32x4;

#define MFMA16(A,B,C) __builtin_amdgcn_mfma_f32_16x16x32_bf16(A,B,C,0,0,0)

constexpr int NTOK = 49;
constexpr int CH   = 128;
// softmax scale folded into exp2: SCALE * log2(e)
constexpr float CEXP = 0.17677669529663687f * 1.4426950408889634f;

__device__ __forceinline__ bf16x8 lds_v8(const u16* base, int byteoff) {
    return *reinterpret_cast<const bf16x8*>(reinterpret_cast<const char*>(base) + byteoff);
}
// 16B fragment load from 8B-aligned address (stride-72 rows): two b64 reads
__device__ __forceinline__ bf16x8 lds_v8_u8(const u16* base, int byteoff) {
    bf16x4 lo = *reinterpret_cast<const bf16x4*>(reinterpret_cast<const char*>(base) + byteoff);
    bf16x4 hi = *reinterpret_cast<const bf16x4*>(reinterpret_cast<const char*>(base) + byteoff + 8);
    bf16x8 r;
    r[0]=lo[0]; r[1]=lo[1]; r[2]=lo[2]; r[3]=lo[3];
    r[4]=hi[0]; r[5]=hi[1]; r[6]=hi[2]; r[7]=hi[3];
    return r;
}
__device__ __forceinline__ void lds_st16(u16* base, int byteoff, bf16 v) {
    *reinterpret_cast<bf16*>(reinterpret_cast<char*>(base) + byteoff) = v;
}

// Convert weights fp32 -> bf16, TRANSPOSED so MFMA B-fragments read contiguous K.
// ws layout: Wqkv_t[384][128] then Wproj_t[128][128]
__global__ void prep_weights_kernel(const float* __restrict__ wqkv,
                                    const float* __restrict__ wproj,
                                    bf16* __restrict__ ws) {
    int i = blockIdx.x * 256 + threadIdx.x;
    if (i < 384 * 128) {
        int n = i >> 7, k = i & 127;
        ws[i] = (bf16)wqkv[k * 384 + n];
    }
    if (i < 128 * 128) {
        int n = i >> 7, k = i & 127;
        ws[384 * 128 + i] = (bf16)wproj[k * 128 + n];
    }
}

// LDS layout (u16 elems), total 26624 elems = 53,248 B  ->  3 blocks/CU:
//   [0, 8192)      Xs : x tile [64 rows][128 ch] bf16, 256B rows, byte^=((row&7)<<4)
//                  ALIAS 1: Vt[h] = Xs + h*2048 : V^T [32 dh][64 seq], 128B swz rows
//                           (written in phase 1 AFTER Xs consumed into af regs)
//                  ALIAS 2: O tile (same layout as Xs), written after PV reads done
//   [8192, 26624)  QK : Qs[h] = QK + h*2304          [64 rows][36] (72B rows, +4 pad)
//                       Ks[h] = QK + 9216 + h*2304   [64 rows][36]
//                  ALIAS: Pb[wv] = QK + wv*4096 : P [64][64], 128B swz rows
//                         (written AFTER q/k fragments consumed into regs)
__launch_bounds__(256, 3)
__global__ void fused_window_attn(const float* __restrict__ x,
                                  const bf16* __restrict__ wqkv_t,
                                  const bf16* __restrict__ wproj_t,
                                  const float* __restrict__ bias,
                                  float* __restrict__ out) {
    __shared__ __align__(16) u16 smem[26624];
    u16* Xs = smem;
    u16* QK = smem + 8192;

    const int tid  = threadIdx.x;
    const int blk  = blockIdx.x;
    const int wv   = tid >> 6;
    const int lane = tid & 63;
    const int lr   = lane & 15;   // A row / B col / D col within 16x16 tile
    const int lg   = lane >> 4;   // k-group for A/B; row-group for D

    // ---------- phase 0: stage x -> Xs (bf16, swizzled); zero pad rows 49..63 ----------
    const float* xw = x + (size_t)blk * (NTOK * CH);
    #pragma unroll
    for (int it = 0; it < 7; ++it) {
        int i = tid + it * 256;
        if (i < (NTOK * CH) / 4) {
            float4 v = reinterpret_cast<const float4*>(xw)[i];
            int e = i * 4, row = e >> 7, col = e & 127;
            bf16x4 pk = { (bf16)v.x, (bf16)v.y, (bf16)v.z, (bf16)v.w };
            *reinterpret_cast<bf16x4*>(reinterpret_cast<char*>(Xs)
                + row * 256 + ((col * 2) ^ ((row & 7) << 4))) = pk;
        }
    }
    if (tid < 240) {  // rows 49..63 = exact zeros -> pad propagates as 0 everywhere
        uint4 zz = {0, 0, 0, 0};
        *reinterpret_cast<uint4*>(reinterpret_cast<char*>(Xs) + 49 * 256 + tid * 16) = zz;
    }
    __syncthreads();

    // ---------- phase 1a: consume Xs into A-fragments (all waves) ----------
    bf16x8 af[4][4];  // [mtile][kstep]
    #pragma unroll
    for (int mt = 0; mt < 4; ++mt)
        #pragma unroll
        for (int ks = 0; ks < 4; ++ks) {
            int row = mt * 16 + lr;
            af[mt][ks] = lds_v8(Xs, row * 256 + ((ks * 64 + lg * 16) ^ ((row & 7) << 4)));
        }
    __syncthreads();  // Xs dead; V writes may now clobber it

    // ---------- phase 1b: QKV GEMM (64x128 @ 128x384), scatter to Q/K/Vt ----------
    #pragma unroll
    for (int i = 0; i < 6; ++i) {          // wave owns 6 of the 24 n-tiles
        int ntg = wv * 6 + i;
        int c   = ntg * 16 + lr;           // output channel of this lane
        bf16x8 bw[4];
        const bf16* wrow = wqkv_t + c * 128 + lg * 8;
        #pragma unroll
        for (int ks = 0; ks < 4; ++ks)
            bw[ks] = *reinterpret_cast<const bf16x8*>(wrow + ks * 32);
        #pragma unroll
        for (int mt = 0; mt < 4; ++mt) {
            f32x4 a = {0.f, 0.f, 0.f, 0.f};
            #pragma unroll
            for (int ks = 0; ks < 4; ++ks) a = MFMA16(af[mt][ks], bw[ks], a);
            #pragma unroll
            for (int rg = 0; rg < 4; ++rg) {
                int r = mt * 16 + lg * 4 + rg;   // token row (pad rows are 0 -> safe)
                bf16 vb = (bf16)a[rg];
                if (c < 128) {
                    QK[(c >> 5) * 2304 + r * 36 + (c & 31)] = __builtin_bit_cast(u16, vb);
                } else if (c < 256) {
                    int cc = c - 128;
                    QK[9216 + (cc >> 5) * 2304 + r * 36 + (cc & 31)] = __builtin_bit_cast(u16, vb);
                } else {
                    int cc = c - 256, dh = cc & 31;
                    lds_st16(Xs + (cc >> 5) * 2048,
                             dh * 128 + ((r * 2) ^ ((dh & 7) << 4)), vb);
                }
            }
        }
    }
    __syncthreads();

    // ---------- phase 2: per-head attention (wave wv == head h) ----------
    const int h = wv;
    const u16* Qh = QK + h * 2304;
    const u16* Kh = QK + 9216 + h * 2304;
    bf16x8 qf[4], kf[4];
    #pragma unroll
    for (int t = 0; t < 4; ++t) {
        qf[t] = lds_v8_u8(Qh, (t * 16 + lr) * 72 + lg * 16);
        kf[t] = lds_v8_u8(Kh, (t * 16 + lr) * 72 + lg * 16);
    }
    __syncthreads();  // Q/K dead; Pb writes may now clobber the QK region

    f32x4 s[4][4];
    #pragma unroll
    for (int mt = 0; mt < 4; ++mt)
        #pragma unroll
        for (int nt = 0; nt < 4; ++nt) {
            f32x4 z = {0.f, 0.f, 0.f, 0.f};
            s[mt][nt] = MFMA16(qf[mt], kf[nt], z);  // S = q @ k^T (K=32, one step)
        }
    // mask seq columns >= 49 (nt==3, lr>=1) -> P cols 49..63 become exact 0
    if (lr >= 1) {
        #pragma unroll
        for (int mt = 0; mt < 4; ++mt)
            #pragma unroll
            for (int rg = 0; rg < 4; ++rg) s[mt][3][rg] = -1e30f;
    }
    // wave-parallel softmax: rows live in 16-lane groups; reduce cols via shfl_xor
    float rs[4][4];
    #pragma unroll
    for (int mt = 0; mt < 4; ++mt) {
        #pragma unroll
        for (int rg = 0; rg < 4; ++rg) {
            float m = fmaxf(fmaxf(s[mt][0][rg], s[mt][1][rg]),
                            fmaxf(s[mt][2][rg], s[mt][3][rg]));
            #pragma unroll
            for (int d = 1; d < 16; d <<= 1) m = fmaxf(m, __shfl_xor(m, d));
            float l = 0.f;
            #pragma unroll
            for (int nt = 0; nt < 4; ++nt) {
                float e = exp2f((s[mt][nt][rg] - m) * CEXP);
                s[mt][nt][rg] = e;
                l += e;
            }
            #pragma unroll
            for (int d = 1; d < 16; d <<= 1) l += __shfl_xor(l, d);
            rs[mt][rg] = 1.f / l;   // fold normalization into O rescale
        }
    }
    // unnormalized P -> Pb (bf16, swizzled); per-wave region, wave-local RAW only
    u16* Pw = QK + wv * 4096;
    #pragma unroll
    for (int mt = 0; mt < 4; ++mt)
        #pragma unroll
        for (int nt = 0; nt < 4; ++nt)
            #pragma unroll
            for (int rg = 0; rg < 4; ++rg) {
                int row = mt * 16 + lg * 4 + rg;
                int col = nt * 16 + lr;
                lds_st16(Pw, row * 128 + ((col * 2) ^ ((row & 7) << 4)),
                         (bf16)s[mt][nt][rg]);
            }
    // O = P @ V  (K = 64 padded seq; V pad cols are exact 0)
    const u16* Vh = Xs + h * 2048;
    f32x4 o[4][2];
    #pragma unroll
    for (int mt = 0; mt < 4; ++mt) {
        f32x4 z = {0.f, 0.f, 0.f, 0.f};
        o[mt][0] = z; o[mt][1] = z;
    }
    #pragma unroll
    for (int ks = 0; ks < 2; ++ks) {
        bf16x8 vf2[2];
        #pragma unroll
        for (int ot = 0; ot < 2; ++ot) {
            int vr = ot * 16 + lr;  // dh row of Vt
            vf2[ot] = lds_v8(Vh, vr * 128 + ((ks * 64 + lg * 16) ^ ((vr & 7) << 4)));
        }
        #pragma unroll
        for (int mt = 0; mt < 4; ++mt) {
            int pr = mt * 16 + lr;
            bf16x8 pf = lds_v8(Pw, pr * 128 + ((ks * 64 + lg * 16) ^ ((pr & 7) << 4)));
            #pragma unroll
            for (int ot = 0; ot < 2; ++ot) o[mt][ot] = MFMA16(pf, vf2[ot], o[mt][ot]);
        }
    }
    __syncthreads();  // all PV reads of Vt done; O writes may now clobber Xs

    // rescale by 1/rowsum, write O tile into Xs
    #pragma unroll
    for (int mt = 0; mt < 4; ++mt)
        #pragma unroll
        for (int ot = 0; ot < 2; ++ot)
            #pragma unroll
            for (int rg = 0; rg < 4; ++rg) {
                int r = mt * 16 + lg * 4 + rg;
                int c = h * 32 + ot * 16 + lr;
                lds_st16(Xs, r * 256 + ((c * 2) ^ ((r & 7) << 4)),
                         (bf16)(o[mt][ot][rg] * rs[mt][rg]));
            }
    __syncthreads();

    // ---------- phase 3: proj GEMM (49x128 @ 128x128) + bias ----------
    bf16x8 ofr[4][4];
    #pragma unroll
    for (int mt = 0; mt < 4; ++mt)
        #pragma unroll
        for (int ks = 0; ks < 4; ++ks) {
            int row = mt * 16 + lr;
            ofr[mt][ks] = lds_v8(Xs, row * 256 + ((ks * 64 + lg * 16) ^ ((row & 7) << 4)));
        }
    #pragma unroll
    for (int i = 0; i < 2; ++i) {          // wave owns 2 of the 8 n-tiles
        int ntg = wv * 2 + i;
        int c   = ntg * 16 + lr;
        bf16x8 bw[4];
        const bf16* wrow = wproj_t + c * 128 + lg * 8;
        #pragma unroll
        for (int ks = 0; ks < 4; ++ks)
            bw[ks] = *reinterpret_cast<const bf16x8*>(wrow + ks * 32);
        float bv = bias[c];
        #pragma unroll
        for (int mt = 0; mt < 4; ++mt) {
            f32x4 a = {0.f, 0.f, 0.f, 0.f};
            #pragma unroll
            for (int ks = 0; ks < 4; ++ks) a = MFMA16(ofr[mt][ks], bw[ks], a);
            #pragma unroll
            for (int rg = 0; rg < 4; ++rg) {
                int r = mt * 16 + lg * 4 + rg;
                if (r < NTOK)
                    out[((size_t)blk * NTOK + r) * CH + c] = a[rg] + bv;
            }
        }
    }
}

extern "C" void kernel_launch(void* const* d_in, const int* in_sizes, int n_in,
                              void* d_out, int out_size, void* d_ws, size_t ws_size,
                              hipStream_t stream) {
    const float* x     = (const float*)d_in[0];
    const float* wqkv  = (const float*)d_in[1];
    const float* wproj = (const float*)d_in[2];
    const float* bias  = (const float*)d_in[3];
    float* out = (float*)d_out;
    bf16* ws   = (bf16*)d_ws;

    constexpr size_t WS_NEED = (size_t)(384 * 128 + 128 * 128) * sizeof(u16);
    if (ws_size < WS_NEED) return;  // scratch too small: fail visibly (zero output)

    prep_weights_kernel<<<192, 256, 0, stream>>>(wqkv, wproj, ws);
    fused_window_attn<<<4096, 256, 0, stream>>>(x, ws, ws + 384 * 128, bias, out);
}